// Round 6
// baseline (84.217 us; speedup 1.0000x reference)
//
#include <hip/hip_runtime.h>

#define FLT_BIG 3.402823466e38f

// tie-break matches jax.lax.top_k: higher value wins; equal values -> lower index wins
static __device__ __forceinline__ bool better(float v1, int i1, float v2, int i2) {
  return (v1 > v2) || ((v1 == v2) && (i1 < i2));
}

// km[h][n][e] = mean_j x[(n*32+j)*256 + h*32+e]
__global__ void kmean_kernel(const float* __restrict__ x, float* __restrict__ km) {
  const int n = blockIdx.x;        // ball
  const int t = threadIdx.x;       // h*32+e
  const float* base = x + n * 32 * 256 + t;
  float acc = 0.f;
  #pragma unroll
  for (int j = 0; j < 32; ++j) acc += base[j * 256];
  const int h = t >> 5, e = t & 31;
  km[h * 8192 + n * 32 + e] = acc * (1.0f / 32.0f);
}

// Block = (head h, 128-query group qb, 64-ball quarter bq). Thread tile 8q x 4b.
// acc=32 VGPR keeps the inner-loop live set (~62) under the compiler's budget so
// all 12 ds_read_b128 per k-step stay in flight (round 5 was latency-bound:
// 80-VGPR cap vs 115 live -> serialized fragment loads).
__global__ __launch_bounds__(256) void select_kernel(const float* __restrict__ x,
                                                     const float* __restrict__ km,
                                                     float4* __restrict__ part) {
  __shared__ float smem[8704];     // 34 KB: GEMM uses 6144, merge uses 8704
  const int bid = blockIdx.x;
  const int h = bid >> 8;          // same-head blocks contiguous -> L2 reuse of km[h]
  const int qb = (bid >> 2) & 63;  // 128-query group (4 adjacent quarters share q rows)
  const int bq = bid & 3;          // ball quarter (64 balls)
  const int t = threadIdx.x;
  const int tq = t >> 4;           // 0..15 : rows 8*tq+i
  const int tb = t & 15;           // 0..15 : local balls tb+16*jj, jj=0..3

  float4* km4 = (float4*)smem;            // 64 balls x 8 chunks, chunk c at b*8 + (c ^ (b&7))
  float4* q4 = (float4*)(smem + 2048);    // 128 rows x 8 chunks, chunk c at r*8 + (c ^ ((r>>3)&7))

  // ---- stage km quarter (coalesced global, swizzled LDS) ----
  {
    const float4* src = (const float4*)km + h * 2048 + bq * 512;
    #pragma unroll
    for (int k = 0; k < 2; ++k) {
      const int idx = t + 256 * k;           // 0..511
      const float4 v = src[idx];
      const int ball = idx >> 3, c = idx & 7;
      km4[ball * 8 + (c ^ (ball & 7))] = v;
    }
  }
  // ---- stage q rows (8 lanes per 128B row-slice, swizzled LDS) ----
  {
    #pragma unroll
    for (int k = 0; k < 4; ++k) {
      const int idx = t + 256 * k;           // 0..1023
      const int r = idx >> 3, c = idx & 7;
      const float4 v = *(const float4*)(x + (qb * 128 + r) * 256 + h * 32 + c * 4);
      q4[r * 8 + (c ^ ((r >> 3) & 7))] = v;
    }
  }
  __syncthreads();

  // ---- GEMM: acc[i][jj] = q[8tq+i] . km[tb+16jj] ----
  float acc[8][4];
  #pragma unroll
  for (int i = 0; i < 8; ++i)
    #pragma unroll
    for (int jj = 0; jj < 4; ++jj) acc[i][jj] = 0.f;

  const int swq = tq & 7, swb = tb & 7;
  #pragma unroll
  for (int s = 0; s < 8; ++s) {
    const int ck = s ^ swb, cq = s ^ swq;
    const float4 kf0 = km4[tb * 8 + ck];
    const float4 kf1 = km4[tb * 8 + 128 + ck];
    const float4 kf2 = km4[tb * 8 + 256 + ck];
    const float4 kf3 = km4[tb * 8 + 384 + ck];
    #pragma unroll
    for (int i = 0; i < 8; ++i) {
      const float4 qf = q4[(8 * tq + i) * 8 + cq];
      acc[i][0] = fmaf(qf.x, kf0.x, acc[i][0]); acc[i][0] = fmaf(qf.y, kf0.y, acc[i][0]);
      acc[i][0] = fmaf(qf.z, kf0.z, acc[i][0]); acc[i][0] = fmaf(qf.w, kf0.w, acc[i][0]);
      acc[i][1] = fmaf(qf.x, kf1.x, acc[i][1]); acc[i][1] = fmaf(qf.y, kf1.y, acc[i][1]);
      acc[i][1] = fmaf(qf.z, kf1.z, acc[i][1]); acc[i][1] = fmaf(qf.w, kf1.w, acc[i][1]);
      acc[i][2] = fmaf(qf.x, kf2.x, acc[i][2]); acc[i][2] = fmaf(qf.y, kf2.y, acc[i][2]);
      acc[i][2] = fmaf(qf.z, kf2.z, acc[i][2]); acc[i][2] = fmaf(qf.w, kf2.w, acc[i][2]);
      acc[i][3] = fmaf(qf.x, kf3.x, acc[i][3]); acc[i][3] = fmaf(qf.y, kf3.y, acc[i][3]);
      acc[i][3] = fmaf(qf.z, kf3.z, acc[i][3]); acc[i][3] = fmaf(qf.w, kf3.w, acc[i][3]);
    }
  }
  __syncthreads();   // done reading km4/q4; smem is reused below

  // merge arrays: [128][17] stride-17 rows (17t mod 32 bijective -> conflict-free)
  float* c_v1 = smem;
  float* c_v2 = smem + 2176;
  float* c_id = smem + 4352;
  float* c_es = smem + 6528;   // ends 8704

  // ---- per-thread top2 + expsum over its 4 balls, per q-row ----
  #pragma unroll
  for (int i = 0; i < 8; ++i) {
    const int r = 8 * tq + i;
    float v[4];
    #pragma unroll
    for (int jj = 0; jj < 4; ++jj) v[jj] = acc[i][jj] * 0.0625f;   // scale = 256^-0.5
    float v1 = v[0]; int i1 = tb;
    float v2 = -FLT_BIG; int i2 = 0;
    #pragma unroll
    for (int jj = 1; jj < 4; ++jj) {
      const int idx = tb + 16 * jj;
      if (better(v[jj], idx, v1, i1)) { v2 = v1; i2 = i1; v1 = v[jj]; i1 = idx; }
      else if (better(v[jj], idx, v2, i2)) { v2 = v[jj]; i2 = idx; }
    }
    float es = 0.f;
    #pragma unroll
    for (int jj = 0; jj < 4; ++jj) es += __expf(v[jj] - v1);
    c_v1[r * 17 + tb] = v1;
    c_v2[r * 17 + tb] = v2;
    c_id[r * 17 + tb] = __int_as_float(i1 | (i2 << 8));
    c_es[r * 17 + tb] = es;
  }
  __syncthreads();

  // ---- level-1 merge: thread t<128 merges row t's 16 chunks, emits partial ----
  if (t < 128) {
    const int base = t * 17;
    float V1 = c_v1[base], V2 = c_v2[base], E = c_es[base];
    int id = __float_as_int(c_id[base]);
    int I1 = id & 255, I2 = (id >> 8) & 255;
    #pragma unroll
    for (int k = 1; k < 16; ++k) {
      const float nv1 = c_v1[base + k], nv2 = c_v2[base + k], nes = c_es[base + k];
      const int nid = __float_as_int(c_id[base + k]);
      const int ni1 = nid & 255, ni2 = (nid >> 8) & 255;
      const float m = fmaxf(V1, nv1);
      E = E * __expf(V1 - m) + nes * __expf(nv1 - m);
      if (better(nv1, ni1, V1, I1)) {
        if (better(V1, I1, nv2, ni2)) { V2 = V1; I2 = I1; } else { V2 = nv2; I2 = ni2; }
        V1 = nv1; I1 = ni1;
      } else if (better(nv1, ni1, V2, I2)) { V2 = nv1; I2 = ni1; }
    }
    const int task = h * 8192 + qb * 128 + t;
    const int gI1 = I1 + bq * 64, gI2 = I2 + bq * 64;
    part[task * 4 + bq] = make_float4(V1, V2, __int_as_float(gI1 | (gI2 << 16)), E);
  }
}

// combine the four 64-ball quarters: global top2 + exact mask semantics
__global__ __launch_bounds__(256) void merge4_kernel(const float4* __restrict__ part,
                                                     int2* __restrict__ sel) {
  const int task = blockIdx.x * 256 + threadIdx.x;   // 0..65535
  const float4 a = part[task * 4 + 0];
  float V1 = a.x, V2 = a.y, E = a.w;
  int id = __float_as_int(a.z);
  int I1 = id & 65535, I2 = id >> 16;
  #pragma unroll
  for (int c = 1; c < 4; ++c) {
    const float4 b = part[task * 4 + c];
    const float nv1 = b.x, nv2 = b.y, nes = b.w;
    const int nid = __float_as_int(b.z);
    const int ni1 = nid & 65535, ni2 = nid >> 16;
    const float m = fmaxf(V1, nv1);
    E = E * __expf(V1 - m) + nes * __expf(nv1 - m);
    if (better(nv1, ni1, V1, I1)) {
      if (better(V1, I1, nv2, ni2)) { V2 = V1; I2 = I1; } else { V2 = nv2; I2 = ni2; }
      V1 = nv1; I1 = ni1;
    } else if (better(nv1, ni1, V2, I2)) { V2 = nv1; I2 = ni1; }
  }
  const float topv1 = 1.0f / E;
  const float topv2 = __expf(V2 - V1) / E;
  const int o1 = (topv1 > 1e-10f) ? I1 : -1;
  const int o2 = (topv2 > 1e-10f) ? I2 : -1;
  sel[task] = make_int2(o1, o2);
}

// one wave per (h, q) task; 64 gathered keys from the 2 selected balls
__global__ __launch_bounds__(256) void attn_kernel(const float* __restrict__ x,
                                                   const int2* __restrict__ sel,
                                                   float* __restrict__ out) {
  __shared__ float p_lds[4 * 64];
  const int lane = threadIdx.x & 63;
  const int widx = threadIdx.x >> 6;
  const int task = blockIdx.x * 4 + widx;   // h*8192 + q
  const int h = task >> 13;
  const int q = task & 8191;

  const int2 sv = sel[task];
  const int iA = sv.x, iB = sv.y;
  const int bA = iA < 0 ? 0 : iA;
  const int bB = iB < 0 ? 0 : iB;

  const int ro = lane >> 3;          // row within 8-row group
  const int o = lane & 7;            // 16B chunk within row-slice
  const float4 qf = *(const float4*)(x + q * 256 + h * 32 + o * 4);

  // ---- key dots: 8 lanes per row (8 x 128B segments/instr) ----
  float dA[4], dB[4];
  #pragma unroll
  for (int i = 0; i < 4; ++i) {
    const float4 ka = *(const float4*)(x + (bA * 32 + i * 8 + ro) * 256 + h * 32 + o * 4);
    float a = qf.x * ka.x; a = fmaf(qf.y, ka.y, a); a = fmaf(qf.z, ka.z, a); a = fmaf(qf.w, ka.w, a);
    dA[i] = a;
    const float4 kb = *(const float4*)(x + (bB * 32 + i * 8 + ro) * 256 + h * 32 + o * 4);
    float bb = qf.x * kb.x; bb = fmaf(qf.y, kb.y, bb); bb = fmaf(qf.z, kb.z, bb); bb = fmaf(qf.w, kb.w, bb);
    dB[i] = bb;
  }
  #pragma unroll
  for (int m = 1; m <= 4; m <<= 1) {
    #pragma unroll
    for (int i = 0; i < 4; ++i) {
      dA[i] += __shfl_xor(dA[i], m);
      dB[i] += __shfl_xor(dB[i], m);
    }
  }

  // ---- masked softmax over 64 slots (values replicated 8x across o-lanes) ----
  float lA[4], lB[4];
  float mx = -FLT_BIG;
  #pragma unroll
  for (int i = 0; i < 4; ++i) {
    lA[i] = (iA >= 0) ? dA[i] * 0.0625f : -FLT_BIG;
    lB[i] = (iB >= 0) ? dB[i] * 0.0625f : -FLT_BIG;
    mx = fmaxf(mx, fmaxf(lA[i], lB[i]));
  }
  #pragma unroll
  for (int m = 8; m <= 32; m <<= 1) mx = fmaxf(mx, __shfl_xor(mx, m));
  float pA[4], pB[4], psum = 0.f;
  #pragma unroll
  for (int i = 0; i < 4; ++i) {
    pA[i] = __expf(lA[i] - mx);
    pB[i] = __expf(lB[i] - mx);
    psum += pA[i] + pB[i];
  }
  #pragma unroll
  for (int m = 8; m <= 32; m <<= 1) psum += __shfl_xor(psum, m);

  // ---- stash p to LDS (one writer lane per row) ----
  const int wbase = widx * 64;
  #pragma unroll
  for (int i = 0; i < 4; ++i) {
    if ((lane & 7) == i) {
      p_lds[wbase + 8 * i + ro] = pA[i];
      p_lds[wbase + 32 + 8 * i + ro] = pB[i];
    }
  }

  // ---- PV: lane (t2,e) sums 32 rows of its ball; V re-read transposed (L1-hot) ----
  const int t2 = lane >> 5;
  const int e = lane & 31;
  const int bP = t2 ? bB : bA;
  const float* vp = x + bP * 32 * 256 + h * 32 + e;
  float acc = 0.f;
  #pragma unroll
  for (int s = 0; s < 32; ++s) {
    float w = p_lds[wbase + t2 * 32 + s];   // broadcast read
    acc = fmaf(w, vp[s * 256], acc);
  }
  acc += __shfl_xor(acc, 32);
  if (lane < 32) out[q * 256 + h * 32 + e] = acc / psum;
}

extern "C" void kernel_launch(void* const* d_in, const int* in_sizes, int n_in,
                              void* d_out, int out_size, void* d_ws, size_t ws_size,
                              hipStream_t stream) {
  const float* x = (const float*)d_in[0];   // (8192, 256) fp32; pos (d_in[1]) is dead code
  float* km = (float*)d_ws;                                   // 256 KB
  float4* part = (float4*)((char*)d_ws + 262144);             // 4 MB (65536 tasks x 4 quarters)
  int2* sel = (int2*)((char*)d_ws + 262144 + 4194304);        // 512 KB
  float* out = (float*)d_out;

  kmean_kernel<<<256, 256, 0, stream>>>(x, km);
  select_kernel<<<2048, 256, 0, stream>>>(x, km, part);
  merge4_kernel<<<256, 256, 0, stream>>>(part, sel);
  attn_kernel<<<16384, 256, 0, stream>>>(x, sel, out);
}